// Round 3
// baseline (327.034 us; speedup 1.0000x reference)
//
#include <hip/hip_runtime.h>
#include <stdint.h>

// Problem constants
#define B_   2
#define S_   2048
#define D_   768
#define H_   12
#define DH_  64
#define N3_  2304   // 3*D
#define M_   4096   // B*S

typedef __attribute__((ext_vector_type(8))) short   bf16x8;
typedef __attribute__((ext_vector_type(4))) float   f32x4;
typedef __attribute__((ext_vector_type(4))) int     i32x4;
typedef __attribute__((ext_vector_type(4))) unsigned short u16x4;

// fold 1/sqrt(dh) * log2(e) into K at write time -> scores exit MFMA in exp2 domain
#define KSCALE 0.18033688011112042f

__device__ inline unsigned short f2bf(float f) {
    union { float f; unsigned u; } v; v.f = f;
    unsigned r = v.u + 0x7FFFu + ((v.u >> 16) & 1u);   // RNE
    return (unsigned short)(r >> 16);
}

// ---------------------------------------------------------------------------
// Prep: fp32 -> bf16 elementwise (vectorized x4)
__global__ void cvt_bf16(const float* __restrict__ in, unsigned short* __restrict__ out, int n4) {
    int i = blockIdx.x * blockDim.x + threadIdx.x;
    if (i >= n4) return;
    f32x4 v = *(const f32x4*)(in + (size_t)i * 4);
    u16x4 o;
    o.x = f2bf(v.x); o.y = f2bf(v.y); o.z = f2bf(v.z); o.w = f2bf(v.w);
    *(u16x4*)(out + (size_t)i * 4) = o;
}

// Prep: transpose fp32 [R][C] -> bf16 [C][R]
__global__ void transpose_bf16(const float* __restrict__ in, unsigned short* __restrict__ out,
                               int R, int C) {
    int id = blockIdx.x * blockDim.x + threadIdx.x;
    if (id >= R * C) return;
    int c = id / R;
    int r = id - c * R;
    out[id] = f2bf(in[(size_t)r * C + c]);
}

// ---------------------------------------------------------------------------
// bf16 MFMA GEMM: C[M][N] = A[M][K] * Bt[N][K]^T + bias
// MODE 0: epilogue scatters bf16 into Q/K [B*H][S][dh] and V^T [B*H][dh][S];
//         K is scaled by KSCALE (exp2-domain fold).
// MODE 1: epilogue writes fp32 C row-major to Cout
template <int MODE>
__global__ __launch_bounds__(256) void gemm_bf16(
    const unsigned short* __restrict__ A,
    const unsigned short* __restrict__ Bt,
    const float* __restrict__ bias,
    void* __restrict__ Cout,
    int M, int N, int K)
{
    __shared__ __align__(16) short Al[128 * 40];
    __shared__ __align__(16) short Bl[128 * 40];

    const int tid  = threadIdx.x;
    const int w    = tid >> 6;
    const int lane = tid & 63;
    const int r    = lane & 15;
    const int quad = lane >> 4;
    const int m0   = blockIdx.y * 128;
    const int n0   = blockIdx.x * 128;
    const int wm   = (w & 1) * 64;
    const int wn   = (w >> 1) * 64;

    f32x4 acc[4][4];
#pragma unroll
    for (int i = 0; i < 4; i++)
#pragma unroll
        for (int j = 0; j < 4; j++) acc[i][j] = f32x4{0.f, 0.f, 0.f, 0.f};

    for (int k0 = 0; k0 < K; k0 += 32) {
        __syncthreads();
#pragma unroll
        for (int p = 0; p < 2; p++) {
            int c   = p * 256 + tid;
            int row = c >> 2;
            int cc  = c & 3;
            *(i32x4*)&Al[row * 40 + cc * 8] =
                *(const i32x4*)&A[(size_t)(m0 + row) * K + k0 + cc * 8];
            *(i32x4*)&Bl[row * 40 + cc * 8] =
                *(const i32x4*)&Bt[(size_t)(n0 + row) * K + k0 + cc * 8];
        }
        __syncthreads();

        bf16x8 af[4], bf[4];
#pragma unroll
        for (int mi = 0; mi < 4; mi++)
            af[mi] = *(const bf16x8*)&Al[(wm + mi * 16 + r) * 40 + quad * 8];
#pragma unroll
        for (int ni = 0; ni < 4; ni++)
            bf[ni] = *(const bf16x8*)&Bl[(wn + ni * 16 + r) * 40 + quad * 8];
#pragma unroll
        for (int mi = 0; mi < 4; mi++)
#pragma unroll
            for (int ni = 0; ni < 4; ni++)
                acc[mi][ni] = __builtin_amdgcn_mfma_f32_16x16x32_bf16(
                    af[mi], bf[ni], acc[mi][ni], 0, 0, 0);
    }

    // Epilogue. C/D layout: col = lane&15 (+16*ni), row = quad*4 + reg (+16*mi)
    if (MODE == 0) {
        unsigned short* Q = (unsigned short*)Cout;   // Q,K,V^T consecutive
        const size_t one = (size_t)B_ * H_ * S_ * DH_;
#pragma unroll
        for (int ni = 0; ni < 4; ni++) {
            int col  = n0 + wn + ni * 16 + r;        // 0..2303
            float bv = bias[col];
            int part = col / 768;                    // 0=q 1=k 2=v
            int cc   = col - part * 768;
            int h    = cc >> 6;
            int d    = cc & 63;
            float scl = (part == 1) ? KSCALE : 1.0f;
            unsigned short* dst = Q + (size_t)part * one;
#pragma unroll
            for (int mi = 0; mi < 4; mi++) {
#pragma unroll
                for (int i = 0; i < 4; i++) {
                    int row = m0 + wm + mi * 16 + quad * 4 + i;  // = b*S + s
                    int b   = row >> 11;
                    int s   = row & 2047;
                    float v = (acc[mi][ni][i] + bv) * scl;
                    if (part < 2)
                        dst[(((size_t)(b * H_ + h)) * S_ + s) * DH_ + d] = f2bf(v);
                    else  // V stored transposed: [B*H][dh][S]
                        dst[(((size_t)(b * H_ + h)) * DH_ + d) * S_ + s] = f2bf(v);
                }
            }
        }
    } else {
        float* Cf = (float*)Cout;
#pragma unroll
        for (int ni = 0; ni < 4; ni++) {
            int col  = n0 + wn + ni * 16 + r;
            float bv = bias[col];
#pragma unroll
            for (int mi = 0; mi < 4; mi++) {
#pragma unroll
                for (int i = 0; i < 4; i++) {
                    int row = m0 + wm + mi * 16 + quad * 4 + i;
                    Cf[(size_t)row * N + col] = acc[mi][ni][i] + bv;
                }
            }
        }
    }
}

// ---------------------------------------------------------------------------
// Flash attention, register-resident / global-direct fragments.
// Q,K: bf16 [B*H][S][64] (K pre-scaled by KSCALE). Vt: bf16 [B*H][64][S].
// Out: bf16 [B][S][D] heads merged. Grid = B*H*(S/64) blocks, 256 thr (4 waves).
// No __syncthreads in the K-loop; only per-wave P transpose uses LDS.
// P tile is 16 rows x 64 cols -> row stride MUST be >= 64; 72 (144 B) keeps
// ds_read_b128 16B-aligned with only free 2-way bank aliasing. (R2's bug: 40.)
__global__ __launch_bounds__(256) void attn_kernel(
    const unsigned short* __restrict__ Q,
    const unsigned short* __restrict__ K,
    const unsigned short* __restrict__ Vt,
    unsigned short* __restrict__ Out)
{
    __shared__ __align__(16) short Pl[4][16 * 72];   // per-wave P [qr][kc], stride 72

    const int tid  = threadIdx.x;
    const int w    = tid >> 6;
    const int lane = tid & 63;
    const int r    = lane & 15;
    const int quad = lane >> 4;
    const int bid  = blockIdx.x;
    const int bh   = bid >> 5;            // 0..23 (consecutive blocks share head -> K/V L2 reuse)
    const int qb   = bid & 31;
    const int b    = bh / H_;
    const int h    = bh - b * H_;
    const size_t baseQK = (size_t)bh * S_ * DH_;
    const size_t baseV  = (size_t)bh * DH_ * S_;
    const int q0   = qb * 64;

    // Q fragments (A-operand: A[m=r][k=quad*8+j]) for this wave's 16 rows
    bf16x8 qf[2];
    {
        const unsigned short* qp = Q + baseQK + (size_t)(q0 + w * 16 + r) * DH_ + quad * 8;
        qf[0] = *(const bf16x8*)(qp);
        qf[1] = *(const bf16x8*)(qp + 32);
    }

    f32x4 o[4];
#pragma unroll
    for (int nb = 0; nb < 4; nb++) o[nb] = f32x4{0.f, 0.f, 0.f, 0.f};
    float lsum[4] = {0.f, 0.f, 0.f, 0.f};

    // B-fragment base pointers (loop-strength-reduced by compiler)
    const unsigned short* kp = K  + baseQK + (size_t)r * DH_ + quad * 8;  // +64*DH_ per kt
    const unsigned short* vp = Vt + baseV  + (size_t)r * S_  + quad * 8;  // +64 per kt
    short* pl = &Pl[w][0];

    for (int kt = 0; kt < 32; kt++) {
        // scores (exp2-domain: KSCALE folded into K)
        f32x4 sa[4];
#pragma unroll
        for (int nb = 0; nb < 4; nb++) sa[nb] = f32x4{0.f, 0.f, 0.f, 0.f};
#pragma unroll
        for (int t = 0; t < 2; t++)
#pragma unroll
            for (int nb = 0; nb < 4; nb++) {
                bf16x8 kf = *(const bf16x8*)(kp + nb * (16 * DH_) + t * 32);
                sa[nb] = __builtin_amdgcn_mfma_f32_16x16x32_bf16(qf[t], kf, sa[nb], 0, 0, 0);
            }

        // p = exp2(s); accumulate per-lane row sums; park P in LDS (A-layout transform)
#pragma unroll
        for (int nb = 0; nb < 4; nb++)
#pragma unroll
            for (int i = 0; i < 4; i++) {
                float p = __builtin_amdgcn_exp2f(sa[nb][i]);
                lsum[i] += p;
                pl[(quad * 4 + i) * 72 + nb * 16 + r] = (short)f2bf(p);
            }

        bf16x8 ap0 = *(const bf16x8*)&pl[r * 72 + quad * 8];
        bf16x8 ap1 = *(const bf16x8*)&pl[r * 72 + 32 + quad * 8];
#pragma unroll
        for (int nb = 0; nb < 4; nb++) {
            bf16x8 v0 = *(const bf16x8*)(vp + (size_t)nb * (16 * S_));
            bf16x8 v1 = *(const bf16x8*)(vp + (size_t)nb * (16 * S_) + 32);
            o[nb] = __builtin_amdgcn_mfma_f32_16x16x32_bf16(ap0, v0, o[nb], 0, 0, 0);
            o[nb] = __builtin_amdgcn_mfma_f32_16x16x32_bf16(ap1, v1, o[nb], 0, 0, 0);
        }

        kp += 64 * DH_;
        vp += 64;
    }

    // epilogue: reduce l across the 16 column-lanes, normalize, store
#pragma unroll
    for (int i = 0; i < 4; i++) {
        float l = lsum[i];
        l += __shfl_xor(l, 1);
        l += __shfl_xor(l, 2);
        l += __shfl_xor(l, 4);
        l += __shfl_xor(l, 8);
        float inv = 1.0f / l;
        int s = q0 + w * 16 + quad * 4 + i;
        size_t ob = ((size_t)b * S_ + s) * D_ + h * DH_;
#pragma unroll
        for (int nb = 0; nb < 4; nb++)
            Out[ob + nb * 16 + r] = f2bf(o[nb][i] * inv);
    }
}

// ---------------------------------------------------------------------------
extern "C" void kernel_launch(void* const* d_in, const int* in_sizes, int n_in,
                              void* d_out, int out_size, void* d_ws, size_t ws_size,
                              hipStream_t stream) {
    const float* x     = (const float*)d_in[0];
    const float* w_in  = (const float*)d_in[1];
    const float* b_in  = (const float*)d_in[2];
    const float* w_out = (const float*)d_in[3];
    const float* b_out = (const float*)d_in[4];
    float* out = (float*)d_out;
    char* ws = (char*)d_ws;

    // workspace layout (bytes)
    unsigned short* xb    = (unsigned short*)(ws);              // 4096x768 bf16
    unsigned short* winT  = (unsigned short*)(ws + 6291456);    // 2304x768 bf16
    unsigned short* woutT = (unsigned short*)(ws + 9830400);    // 768x768 bf16
    unsigned short* QKV   = (unsigned short*)(ws + 11010048);   // Q,K [24][2048][64] + Vt [24][64][2048]
    unsigned short* attn  = (unsigned short*)(ws + 29884416);   // 4096x768 bf16

    const size_t one = (size_t)B_ * H_ * S_ * DH_;

    cvt_bf16<<<3072, 256, 0, stream>>>(x, xb, (M_ * D_) / 4);
    transpose_bf16<<<(D_ * N3_ + 255) / 256, 256, 0, stream>>>(w_in, winT, D_, N3_);
    transpose_bf16<<<(D_ * D_ + 255) / 256, 256, 0, stream>>>(w_out, woutT, D_, D_);

    gemm_bf16<0><<<dim3(N3_ / 128, M_ / 128), 256, 0, stream>>>(
        xb, winT, b_in, (void*)QKV, M_, N3_, D_);

    attn_kernel<<<B_ * H_ * (S_ / 64), 256, 0, stream>>>(
        QKV, QKV + one, QKV + 2 * one, attn);

    gemm_bf16<1><<<dim3(D_ / 128, M_ / 128), 256, 0, stream>>>(
        attn, woutT, b_out, (void*)out, M_, D_, D_);
}

// Round 4
// 187.826 us; speedup vs baseline: 1.7412x; 1.7412x over previous
//
#include <hip/hip_runtime.h>
#include <stdint.h>

// Problem constants
#define B_   2
#define S_   2048
#define D_   768
#define H_   12
#define DH_  64
#define N3_  2304   // 3*D
#define M_   4096   // B*S

typedef __attribute__((ext_vector_type(8))) short   bf16x8;
typedef __attribute__((ext_vector_type(4))) float   f32x4;
typedef __attribute__((ext_vector_type(4))) int     i32x4;
typedef __attribute__((ext_vector_type(4))) unsigned short u16x4;

// fold 1/sqrt(dh) * log2(e) into K at write time -> scores exit MFMA in exp2 domain
#define KSCALE 0.18033688011112042f

__device__ inline unsigned short f2bf(float f) {
    union { float f; unsigned u; } v; v.f = f;
    unsigned r = v.u + 0x7FFFu + ((v.u >> 16) & 1u);   // RNE
    return (unsigned short)(r >> 16);
}

// ---------------------------------------------------------------------------
// Prep: fp32 -> bf16 elementwise (vectorized x4)
__global__ void cvt_bf16(const float* __restrict__ in, unsigned short* __restrict__ out, int n4) {
    int i = blockIdx.x * blockDim.x + threadIdx.x;
    if (i >= n4) return;
    f32x4 v = *(const f32x4*)(in + (size_t)i * 4);
    u16x4 o;
    o.x = f2bf(v.x); o.y = f2bf(v.y); o.z = f2bf(v.z); o.w = f2bf(v.w);
    *(u16x4*)(out + (size_t)i * 4) = o;
}

// Prep: tiled transpose fp32 [R][C] -> bf16 [C][R]; R,C multiples of 32.
// grid (C/32, R/32), block (32,8). Coalesced read AND write via LDS tile.
__global__ void transpose_bf16(const float* __restrict__ in, unsigned short* __restrict__ out,
                               int R, int C) {
    __shared__ unsigned short t[32][33];
    int c0 = blockIdx.x * 32, r0 = blockIdx.y * 32;
    int tx = threadIdx.x, ty = threadIdx.y;
#pragma unroll
    for (int j = 0; j < 4; j++)
        t[ty + j * 8][tx] = f2bf(in[(size_t)(r0 + ty + j * 8) * C + c0 + tx]);
    __syncthreads();
#pragma unroll
    for (int j = 0; j < 4; j++)
        out[(size_t)(c0 + ty + j * 8) * R + r0 + tx] = t[tx][ty + j * 8];
}

// ---------------------------------------------------------------------------
// bf16 MFMA GEMM: C[M][N] = A[M][K] * Bt[N][K]^T + bias
// Register-prefetch pipelined single-buffer LDS (fetch k+1 after 2nd barrier).
// MODE 0: epilogue scatters bf16 into Q/K [B*H][S][dh] and V^T [B*H][dh][S];
//         K is scaled by KSCALE (exp2-domain fold).
// MODE 1: epilogue writes fp32 C row-major to Cout
template <int MODE>
__global__ __launch_bounds__(256) void gemm_bf16(
    const unsigned short* __restrict__ A,
    const unsigned short* __restrict__ Bt,
    const float* __restrict__ bias,
    void* __restrict__ Cout,
    int M, int N, int K)
{
    __shared__ __align__(16) short Al[128 * 40];
    __shared__ __align__(16) short Bl[128 * 40];

    const int tid  = threadIdx.x;
    const int w    = tid >> 6;
    const int lane = tid & 63;
    const int r    = lane & 15;
    const int quad = lane >> 4;
    const int m0   = blockIdx.y * 128;
    const int n0   = blockIdx.x * 128;
    const int wm   = (w & 1) * 64;
    const int wn   = (w >> 1) * 64;

    f32x4 acc[4][4];
#pragma unroll
    for (int i = 0; i < 4; i++)
#pragma unroll
        for (int j = 0; j < 4; j++) acc[i][j] = f32x4{0.f, 0.f, 0.f, 0.f};

    // per-thread staging addresses: c = p*256+tid -> row=c>>2, chunk=c&3
    i32x4 areg[2], breg[2];
    const int arow0 = tid >> 2, acc0 = tid & 3;           // p=0
    const int arow1 = (tid + 256) >> 2, acc1 = tid & 3;   // p=1
    const size_t aoff0 = (size_t)(m0 + arow0) * K + acc0 * 8;
    const size_t aoff1 = (size_t)(m0 + arow1) * K + acc1 * 8;
    const size_t boff0 = (size_t)(n0 + arow0) * K + acc0 * 8;
    const size_t boff1 = (size_t)(n0 + arow1) * K + acc1 * 8;
    const int ld0 = arow0 * 40 + acc0 * 8;
    const int ld1 = arow1 * 40 + acc1 * 8;

    // prologue fetch k0=0
    areg[0] = *(const i32x4*)&A[aoff0];
    areg[1] = *(const i32x4*)&A[aoff1];
    breg[0] = *(const i32x4*)&Bt[boff0];
    breg[1] = *(const i32x4*)&Bt[boff1];

    for (int k0 = 0; k0 < K; k0 += 32) {
        __syncthreads();
        *(i32x4*)&Al[ld0] = areg[0];
        *(i32x4*)&Al[ld1] = areg[1];
        *(i32x4*)&Bl[ld0] = breg[0];
        *(i32x4*)&Bl[ld1] = breg[1];
        __syncthreads();

        if (k0 + 32 < K) {
            int kn = k0 + 32;
            areg[0] = *(const i32x4*)&A[aoff0 + kn];
            areg[1] = *(const i32x4*)&A[aoff1 + kn];
            breg[0] = *(const i32x4*)&Bt[boff0 + kn];
            breg[1] = *(const i32x4*)&Bt[boff1 + kn];
        }

        bf16x8 af[4], bf[4];
#pragma unroll
        for (int mi = 0; mi < 4; mi++)
            af[mi] = *(const bf16x8*)&Al[(wm + mi * 16 + r) * 40 + quad * 8];
#pragma unroll
        for (int ni = 0; ni < 4; ni++)
            bf[ni] = *(const bf16x8*)&Bl[(wn + ni * 16 + r) * 40 + quad * 8];
#pragma unroll
        for (int mi = 0; mi < 4; mi++)
#pragma unroll
            for (int ni = 0; ni < 4; ni++)
                acc[mi][ni] = __builtin_amdgcn_mfma_f32_16x16x32_bf16(
                    af[mi], bf[ni], acc[mi][ni], 0, 0, 0);
    }

    // Epilogue. C/D layout: col = lane&15 (+16*ni), row = quad*4 + reg (+16*mi)
    if (MODE == 0) {
        unsigned short* Q = (unsigned short*)Cout;   // Q,K,V^T consecutive
        const size_t one = (size_t)B_ * H_ * S_ * DH_;
#pragma unroll
        for (int ni = 0; ni < 4; ni++) {
            int col  = n0 + wn + ni * 16 + r;        // 0..2303
            float bv = bias[col];
            int part = col / 768;                    // 0=q 1=k 2=v
            int cc   = col - part * 768;
            int h    = cc >> 6;
            int d    = cc & 63;
            float scl = (part == 1) ? KSCALE : 1.0f;
            unsigned short* dst = Q + (size_t)part * one;
#pragma unroll
            for (int mi = 0; mi < 4; mi++) {
#pragma unroll
                for (int i = 0; i < 4; i++) {
                    int row = m0 + wm + mi * 16 + quad * 4 + i;  // = b*S + s
                    int b   = row >> 11;
                    int s   = row & 2047;
                    float v = (acc[mi][ni][i] + bv) * scl;
                    if (part < 2)
                        dst[(((size_t)(b * H_ + h)) * S_ + s) * DH_ + d] = f2bf(v);
                    else  // V stored transposed: [B*H][dh][S]
                        dst[(((size_t)(b * H_ + h)) * DH_ + d) * S_ + s] = f2bf(v);
                }
            }
        }
    } else {
        float* Cf = (float*)Cout;
#pragma unroll
        for (int ni = 0; ni < 4; ni++) {
            int col  = n0 + wn + ni * 16 + r;
            float bv = bias[col];
#pragma unroll
            for (int mi = 0; mi < 4; mi++) {
#pragma unroll
                for (int i = 0; i < 4; i++) {
                    int row = m0 + wm + mi * 16 + quad * 4 + i;
                    Cf[(size_t)row * N + col] = acc[mi][ni][i] + bv;
                }
            }
        }
    }
}

// ---------------------------------------------------------------------------
// Flash attention, LDS-staged K/Vt tiles + register-prefetch pipeline.
// Q,K: bf16 [B*H][S][64] (K pre-scaled by KSCALE). Vt: bf16 [B*H][64][S].
// Out: bf16 [B][S][D] heads merged. Grid = 768 blocks, 256 thr (4 waves x 16 q).
// bid decode: bh = bid % 24 -> all 32 q-blocks of a head land on XCD bh%8
// (heuristic L2 locality; 3 heads x 512KB = 1.5MB per XCD L2).
__global__ __launch_bounds__(256) void attn_kernel(
    const unsigned short* __restrict__ Q,
    const unsigned short* __restrict__ K,
    const unsigned short* __restrict__ Vt,
    unsigned short* __restrict__ Out)
{
    __shared__ __align__(16) short Kl[64 * 72];      // K tile [kc][d], stride 72
    __shared__ __align__(16) short Vl[64 * 72];      // V^T tile [d][kc], stride 72
    __shared__ __align__(16) short Pl[4][16 * 72];   // per-wave P [qr][kc], stride 72

    const int tid  = threadIdx.x;
    const int w    = tid >> 6;
    const int lane = tid & 63;
    const int r    = lane & 15;
    const int quad = lane >> 4;
    const int bid  = blockIdx.x;
    const int bh   = bid % 24;
    const int qb   = bid / 24;
    const int b    = bh / H_;
    const int h    = bh - b * H_;
    const size_t baseQK = (size_t)bh * S_ * DH_;
    const size_t baseV  = (size_t)bh * DH_ * S_;
    const int q0   = qb * 64;

    // Q fragments (A-operand: A[m=r][k=quad*8+j]) for this wave's 16 rows
    bf16x8 qf[2];
    {
        const unsigned short* qp = Q + baseQK + (size_t)(q0 + w * 16 + r) * DH_ + quad * 8;
        qf[0] = *(const bf16x8*)(qp);
        qf[1] = *(const bf16x8*)(qp + 32);
    }

    f32x4 o[4];
#pragma unroll
    for (int nb = 0; nb < 4; nb++) o[nb] = f32x4{0.f, 0.f, 0.f, 0.f};
    float lsum[4] = {0.f, 0.f, 0.f, 0.f};

    // staging addresses: c = p*256+tid; row=c>>3 (0..63), chunk=c&7
    // K tile rows are contiguous in global (8KB block); Vt rows are S_-strided.
    const int srow = tid >> 3, schk = tid & 7;
    const unsigned short* kgp = K + baseQK + tid * 8;                    // +2048 for p=1
    const unsigned short* vgp = Vt + baseV + (size_t)srow * S_ + schk * 8;  // +32*S_ for p=1
    const int kld = srow * 72 + schk * 8;                                // +32*72 for p=1
    short* pl = &Pl[w][0];

    i32x4 kreg[2], vreg[2];
    kreg[0] = *(const i32x4*)(kgp);
    kreg[1] = *(const i32x4*)(kgp + 2048);
    vreg[0] = *(const i32x4*)(vgp);
    vreg[1] = *(const i32x4*)(vgp + 32 * S_);

    for (int kt = 0; kt < 32; kt++) {
        __syncthreads();
        *(i32x4*)&Kl[kld]           = kreg[0];
        *(i32x4*)&Kl[kld + 32 * 72] = kreg[1];
        *(i32x4*)&Vl[kld]           = vreg[0];
        *(i32x4*)&Vl[kld + 32 * 72] = vreg[1];
        __syncthreads();

        if (kt != 31) {
            const unsigned short* kn = kgp + (kt + 1) * (64 * DH_);
            const unsigned short* vn = vgp + (kt + 1) * 64;
            kreg[0] = *(const i32x4*)(kn);
            kreg[1] = *(const i32x4*)(kn + 2048);
            vreg[0] = *(const i32x4*)(vn);
            vreg[1] = *(const i32x4*)(vn + 32 * S_);
        }

        // scores (exp2-domain: KSCALE folded into K)
        f32x4 sa[4];
#pragma unroll
        for (int nb = 0; nb < 4; nb++) sa[nb] = f32x4{0.f, 0.f, 0.f, 0.f};
#pragma unroll
        for (int t = 0; t < 2; t++)
#pragma unroll
            for (int nb = 0; nb < 4; nb++) {
                bf16x8 kf = *(const bf16x8*)&Kl[(nb * 16 + r) * 72 + t * 32 + quad * 8];
                sa[nb] = __builtin_amdgcn_mfma_f32_16x16x32_bf16(qf[t], kf, sa[nb], 0, 0, 0);
            }

        // p = exp2(s); per-lane row sums; park P in LDS (C-layout -> A-layout)
#pragma unroll
        for (int nb = 0; nb < 4; nb++)
#pragma unroll
            for (int i = 0; i < 4; i++) {
                float p = __builtin_amdgcn_exp2f(sa[nb][i]);
                lsum[i] += p;
                pl[(quad * 4 + i) * 72 + nb * 16 + r] = (short)f2bf(p);
            }

        bf16x8 ap0 = *(const bf16x8*)&pl[r * 72 + quad * 8];
        bf16x8 ap1 = *(const bf16x8*)&pl[r * 72 + 32 + quad * 8];
#pragma unroll
        for (int nb = 0; nb < 4; nb++) {
            bf16x8 v0 = *(const bf16x8*)&Vl[(nb * 16 + r) * 72 + quad * 8];
            bf16x8 v1 = *(const bf16x8*)&Vl[(nb * 16 + r) * 72 + 32 + quad * 8];
            o[nb] = __builtin_amdgcn_mfma_f32_16x16x32_bf16(ap0, v0, o[nb], 0, 0, 0);
            o[nb] = __builtin_amdgcn_mfma_f32_16x16x32_bf16(ap1, v1, o[nb], 0, 0, 0);
        }
    }

    // epilogue: reduce l across the 16 column-lanes, normalize, store
#pragma unroll
    for (int i = 0; i < 4; i++) {
        float l = lsum[i];
        l += __shfl_xor(l, 1);
        l += __shfl_xor(l, 2);
        l += __shfl_xor(l, 4);
        l += __shfl_xor(l, 8);
        float inv = 1.0f / l;
        int s = q0 + w * 16 + quad * 4 + i;
        size_t ob = ((size_t)b * S_ + s) * D_ + h * DH_;
#pragma unroll
        for (int nb = 0; nb < 4; nb++)
            Out[ob + nb * 16 + r] = f2bf(o[nb][i] * inv);
    }
}

// ---------------------------------------------------------------------------
extern "C" void kernel_launch(void* const* d_in, const int* in_sizes, int n_in,
                              void* d_out, int out_size, void* d_ws, size_t ws_size,
                              hipStream_t stream) {
    const float* x     = (const float*)d_in[0];
    const float* w_in  = (const float*)d_in[1];
    const float* b_in  = (const float*)d_in[2];
    const float* w_out = (const float*)d_in[3];
    const float* b_out = (const float*)d_in[4];
    float* out = (float*)d_out;
    char* ws = (char*)d_ws;

    // workspace layout (bytes)
    unsigned short* xb    = (unsigned short*)(ws);              // 4096x768 bf16
    unsigned short* winT  = (unsigned short*)(ws + 6291456);    // 2304x768 bf16
    unsigned short* woutT = (unsigned short*)(ws + 9830400);    // 768x768 bf16
    unsigned short* QKV   = (unsigned short*)(ws + 11010048);   // Q,K [24][2048][64] + Vt [24][64][2048]
    unsigned short* attn  = (unsigned short*)(ws + 29884416);   // 4096x768 bf16

    const size_t one = (size_t)B_ * H_ * S_ * DH_;

    cvt_bf16<<<3072, 256, 0, stream>>>(x, xb, (M_ * D_) / 4);
    transpose_bf16<<<dim3(N3_ / 32, D_ / 32), dim3(32, 8), 0, stream>>>(w_in, winT, D_, N3_);
    transpose_bf16<<<dim3(D_ / 32, D_ / 32), dim3(32, 8), 0, stream>>>(w_out, woutT, D_, D_);

    gemm_bf16<0><<<dim3(N3_ / 128, M_ / 128), 256, 0, stream>>>(
        xb, winT, b_in, (void*)QKV, M_, N3_, D_);

    attn_kernel<<<B_ * H_ * (S_ / 64), 256, 0, stream>>>(
        QKV, QKV + one, QKV + 2 * one, attn);

    gemm_bf16<1><<<dim3(D_ / 128, M_ / 128), 256, 0, stream>>>(
        attn, woutT, b_out, (void*)out, M_, D_, D_);
}